// Round 1
// baseline (167.072 us; speedup 1.0000x reference)
//
#include <hip/hip_runtime.h>
#include <hip/hip_bf16.h>

#define B_DIM 4096
#define I_DIM 2048
#define H_DIM 2048
#define K_DIM 2048   // K per pass for both GEMMs

typedef unsigned short u16;
typedef __attribute__((ext_vector_type(8))) short bf16x8;
typedef __attribute__((ext_vector_type(4))) float f32x4;

// fp32 -> bf16 round-to-nearest-even (bits)
__device__ __forceinline__ u16 f2bf(float f) {
  unsigned u = __float_as_uint(f);
  u += 0x7fffu + ((u >> 16) & 1u);
  return (u16)(u >> 16);
}

__device__ __forceinline__ void gload_lds16(const void* g, void* l) {
  __builtin_amdgcn_global_load_lds(
      (const __attribute__((address_space(1))) void*)g,
      (__attribute__((address_space(3))) void*)l, 16, 0, 0);
}

// ---------------------------------------------------------------------------
// Kernel A: fused fp32->bf16 convert for x (B*I), an (I*H), bn (I*H)
// ---------------------------------------------------------------------------
__global__ void convert_ew(const float* __restrict__ x, const float* __restrict__ an,
                           const float* __restrict__ bn, u16* __restrict__ xb,
                           u16* __restrict__ anb, u16* __restrict__ bnb) {
  const long NX = (long)B_DIM * I_DIM;        // 8388608
  const long NA = (long)I_DIM * H_DIM;        // 4194304
  const long total4 = (NX + 2 * NA) / 4;
  for (long t = (long)blockIdx.x * blockDim.x + threadIdx.x; t < total4;
       t += (long)gridDim.x * blockDim.x) {
    long i4 = t * 4;
    const float* src;
    u16* dst;
    long off;
    if (i4 < NX) { src = x; dst = xb; off = i4; }
    else if (i4 < NX + NA) { src = an; dst = anb; off = i4 - NX; }
    else { src = bn; dst = bnb; off = i4 - NX - NA; }
    float4 v = *(const float4*)(src + off);
    ushort4 o;
    o.x = f2bf(v.x); o.y = f2bf(v.y); o.z = f2bf(v.z); o.w = f2bf(v.w);
    *(ushort4*)(dst + off) = o;
  }
}

// ---------------------------------------------------------------------------
// Kernel B: coeff [I,H] fp32  ->  coeffT [H,I] bf16   (LDS-tiled transpose)
// ---------------------------------------------------------------------------
__global__ void transpose_conv(const float* __restrict__ c, u16* __restrict__ ct) {
  __shared__ float tile[32][33];
  const int i0 = blockIdx.y * 32;
  const int h0 = blockIdx.x * 32;
  const int tx = threadIdx.x;  // 0..31
  const int ty = threadIdx.y;  // 0..7
  for (int r = ty; r < 32; r += 8)
    tile[r][tx] = c[(long)(i0 + r) * H_DIM + (h0 + tx)];
  __syncthreads();
  for (int r = ty; r < 32; r += 8)
    ct[(long)(h0 + r) * I_DIM + (i0 + tx)] = f2bf(tile[tx][r]);
}

// ---------------------------------------------------------------------------
// Shared GEMM K-loop: C128x128 tile += A[M,K](row-major bf16) @ Bt[N,K]^T
// 4 waves (2x2), each wave 64x64 = 4x4 frags of 16x16x32 MFMA. BK=32.
// ---------------------------------------------------------------------------
__device__ __forceinline__ void gemm_kloop(const u16* __restrict__ A,
                                           const u16* __restrict__ Bt,
                                           int rowA0, int colB0,
                                           u16* As, u16* Bs, f32x4 acc[4][4]) {
  const int tid = threadIdx.x;
  const int lane = tid & 63;
  const int wr = (tid >> 6) >> 1;
  const int wc = (tid >> 6) & 1;

  // staging: 4 x 16B per thread per K-step; LDS layout linear row-major [128][32]
  const int o0 = tid * 16;         // bytes, round 0
  const int o1 = 4096 + tid * 16;  // bytes, round 1
  const int r0 = o0 >> 6, c0 = o0 & 63;
  const int r1 = o1 >> 6, c1 = o1 & 63;

  const char* Ab = (const char*)(A + (long)rowA0 * K_DIM);
  const char* Bb = (const char*)(Bt + (long)colB0 * K_DIM);
  char* AsB = (char*)As;
  char* BsB = (char*)Bs;

  const int ar = wr * 64 + (lane & 15);
  const int br = wc * 64 + (lane & 15);
  const int kk = (lane >> 4) * 8;

  for (int kt = 0; kt < K_DIM / 32; ++kt) {
    const long kb = (long)kt * 64;  // byte offset along K
    gload_lds16(Ab + (long)r0 * (K_DIM * 2) + kb + c0, AsB + o0);
    gload_lds16(Ab + (long)r1 * (K_DIM * 2) + kb + c1, AsB + o1);
    gload_lds16(Bb + (long)r0 * (K_DIM * 2) + kb + c0, BsB + o0);
    gload_lds16(Bb + (long)r1 * (K_DIM * 2) + kb + c1, BsB + o1);
    __syncthreads();  // drains vmcnt before barrier -> LDS tiles valid
    bf16x8 a[4], b[4];
#pragma unroll
    for (int m = 0; m < 4; ++m)
      a[m] = *(const bf16x8*)(As + (ar + m * 16) * 32 + kk);
#pragma unroll
    for (int n = 0; n < 4; ++n)
      b[n] = *(const bf16x8*)(Bs + (br + n * 16) * 32 + kk);
#pragma unroll
    for (int m = 0; m < 4; ++m)
#pragma unroll
      for (int n = 0; n < 4; ++n)
        acc[m][n] = __builtin_amdgcn_mfma_f32_16x16x32_bf16(a[m], b[n], acc[m][n], 0, 0, 0);
    __syncthreads();  // protect LDS against next iteration's staging
  }
}

// ---------------------------------------------------------------------------
// Kernel C: GEMM1  phase = xb @ coeffT^T ; epilogue writes cos/sin as bf16
// ---------------------------------------------------------------------------
__global__ __launch_bounds__(256) void gemm_phase(const u16* __restrict__ xb,
                                                  const u16* __restrict__ ct,
                                                  u16* __restrict__ cosP,
                                                  u16* __restrict__ sinP) {
  __shared__ __align__(16) u16 As[128 * 32];
  __shared__ __align__(16) u16 Bs[128 * 32];
  const int rowA0 = blockIdx.y * 128;
  const int colB0 = blockIdx.x * 128;
  f32x4 acc[4][4];
#pragma unroll
  for (int m = 0; m < 4; ++m)
#pragma unroll
    for (int n = 0; n < 4; ++n)
#pragma unroll
      for (int j = 0; j < 4; ++j) acc[m][n][j] = 0.0f;

  gemm_kloop(xb, ct, rowA0, colB0, As, Bs, acc);

  const int lane = threadIdx.x & 63;
  const int wr = (threadIdx.x >> 6) >> 1;
  const int wc = (threadIdx.x >> 6) & 1;
#pragma unroll
  for (int m = 0; m < 4; ++m) {
#pragma unroll
    for (int n = 0; n < 4; ++n) {
      const int col = colB0 + wc * 64 + n * 16 + (lane & 15);
#pragma unroll
      for (int j = 0; j < 4; ++j) {
        const int row = rowA0 + wr * 64 + m * 16 + (lane >> 4) * 4 + j;
        const float p = acc[m][n][j];
        cosP[(long)row * H_DIM + col] = f2bf(__cosf(p));
        sinP[(long)row * H_DIM + col] = f2bf(__sinf(p));
      }
    }
  }
}

// ---------------------------------------------------------------------------
// Kernel D: GEMM2  gain = cosP@an^T + sinP@bn^T + H*bias   (fp32 out)
// ---------------------------------------------------------------------------
__global__ __launch_bounds__(256) void gemm_gain(const u16* __restrict__ cosP,
                                                 const u16* __restrict__ sinP,
                                                 const u16* __restrict__ anb,
                                                 const u16* __restrict__ bnb,
                                                 const float* __restrict__ bias,
                                                 float* __restrict__ out) {
  __shared__ __align__(16) u16 As[128 * 32];
  __shared__ __align__(16) u16 Bs[128 * 32];
  const int rowA0 = blockIdx.y * 128;
  const int colB0 = blockIdx.x * 128;
  f32x4 acc[4][4];
#pragma unroll
  for (int m = 0; m < 4; ++m)
#pragma unroll
    for (int n = 0; n < 4; ++n)
#pragma unroll
      for (int j = 0; j < 4; ++j) acc[m][n][j] = 0.0f;

  gemm_kloop(cosP, anb, rowA0, colB0, As, Bs, acc);
  gemm_kloop(sinP, bnb, rowA0, colB0, As, Bs, acc);

  const int lane = threadIdx.x & 63;
  const int wr = (threadIdx.x >> 6) >> 1;
  const int wc = (threadIdx.x >> 6) & 1;
#pragma unroll
  for (int m = 0; m < 4; ++m) {
#pragma unroll
    for (int n = 0; n < 4; ++n) {
      const int col = colB0 + wc * 64 + n * 16 + (lane & 15);
      const float bv = 2048.0f * bias[col];
#pragma unroll
      for (int j = 0; j < 4; ++j) {
        const int row = rowA0 + wr * 64 + m * 16 + (lane >> 4) * 4 + j;
        out[(long)row * I_DIM + col] = acc[m][n][j] + bv;
      }
    }
  }
}

// ---------------------------------------------------------------------------
extern "C" void kernel_launch(void* const* d_in, const int* in_sizes, int n_in,
                              void* d_out, int out_size, void* d_ws, size_t ws_size,
                              hipStream_t stream) {
  const float* x     = (const float*)d_in[0];
  const float* coeff = (const float*)d_in[1];
  const float* an    = (const float*)d_in[2];
  const float* bn    = (const float*)d_in[3];
  const float* bias  = (const float*)d_in[4];
  float* out = (float*)d_out;

  char* ws = (char*)d_ws;
  u16* xb   = (u16*)(ws);                       // 16 MB  [B,I] bf16
  u16* ct   = (u16*)(ws + (16L << 20));         //  8 MB  [H,I] bf16 (coeff^T)
  u16* anb  = (u16*)(ws + (24L << 20));         //  8 MB  [I,H] bf16
  u16* bnb  = (u16*)(ws + (32L << 20));         //  8 MB  [I,H] bf16
  u16* cosP = (u16*)(ws + (40L << 20));         // 16 MB  [B,H] bf16
  u16* sinP = (u16*)(ws + (56L << 20));         // 16 MB  [B,H] bf16  (total 72 MB)

  convert_ew<<<1024, 256, 0, stream>>>(x, an, bn, xb, anb, bnb);
  transpose_conv<<<dim3(H_DIM / 32, I_DIM / 32), dim3(32, 8), 0, stream>>>(coeff, ct);
  gemm_phase<<<dim3(H_DIM / 128, B_DIM / 128), 256, 0, stream>>>(xb, ct, cosP, sinP);
  gemm_gain<<<dim3(I_DIM / 128, B_DIM / 128), 256, 0, stream>>>(cosP, sinP, anb, bnb, bias, out);
}

// Round 2
// 125.719 us; speedup vs baseline: 1.3289x; 1.3289x over previous
//
#include <hip/hip_runtime.h>
#include <hip/hip_bf16.h>

#define B_DIM 4096
#define I_DIM 2048
#define H_DIM 2048

typedef unsigned short u16;
typedef unsigned int u32;
typedef __attribute__((ext_vector_type(8))) short bf16x8;
typedef __attribute__((ext_vector_type(4))) float f32x4;
typedef __attribute__((ext_vector_type(4))) u32 u32x4;

// fp32 -> bf16 round-to-nearest-even (bits)
__device__ __forceinline__ u16 f2bf(float f) {
  unsigned u = __float_as_uint(f);
  u += 0x7fffu + ((u >> 16) & 1u);
  return (u16)(u >> 16);
}

__device__ __forceinline__ void gload_lds16(const void* g, void* l) {
  __builtin_amdgcn_global_load_lds(
      (const __attribute__((address_space(1))) void*)g,
      (__attribute__((address_space(3))) void*)l, 16, 0, 0);
}

// ---------------------------------------------------------------------------
// Kernel A: fp32->bf16 convert. xb[B,I]; AB[I,2H] interleaved (an,bn) pairs.
// ---------------------------------------------------------------------------
__global__ void convert_ew(const float* __restrict__ x, const float* __restrict__ an,
                           const float* __restrict__ bn, u16* __restrict__ xb,
                           u32* __restrict__ ab) {
  const long NX4 = (long)B_DIM * I_DIM / 4;  // float4 units of x
  const long NA4 = (long)I_DIM * H_DIM / 4;  // float4 units of an (and bn)
  const long total = NX4 + NA4;
  for (long t = (long)blockIdx.x * blockDim.x + threadIdx.x; t < total;
       t += (long)gridDim.x * blockDim.x) {
    if (t < NX4) {
      float4 v = *(const float4*)(x + t * 4);
      ushort4 o;
      o.x = f2bf(v.x); o.y = f2bf(v.y); o.z = f2bf(v.z); o.w = f2bf(v.w);
      *(ushort4*)(xb + t * 4) = o;
    } else {
      long p = (t - NX4) * 4;  // element offset into an/bn
      float4 va = *(const float4*)(an + p);
      float4 vb = *(const float4*)(bn + p);
      u32x4 w;
      w.x = (u32)f2bf(va.x) | ((u32)f2bf(vb.x) << 16);
      w.y = (u32)f2bf(va.y) | ((u32)f2bf(vb.y) << 16);
      w.z = (u32)f2bf(va.z) | ((u32)f2bf(vb.z) << 16);
      w.w = (u32)f2bf(va.w) | ((u32)f2bf(vb.w) << 16);
      *(u32x4*)(ab + p) = w;  // ab[i*2H + 2h] = an, [..+1] = bn
    }
  }
}

// ---------------------------------------------------------------------------
// Kernel B: coeff [I,H] fp32 -> coeffT [H,I] bf16 (LDS-tiled transpose)
// ---------------------------------------------------------------------------
__global__ void transpose_conv(const float* __restrict__ c, u16* __restrict__ ct) {
  __shared__ float tile[32][33];
  const int i0 = blockIdx.y * 32;
  const int h0 = blockIdx.x * 32;
  const int tx = threadIdx.x;  // 0..31
  const int ty = threadIdx.y;  // 0..7
  for (int r = ty; r < 32; r += 8)
    tile[r][tx] = c[(long)(i0 + r) * H_DIM + (h0 + tx)];
  __syncthreads();
  for (int r = ty; r < 32; r += 8)
    ct[(long)(h0 + r) * I_DIM + (i0 + tx)] = f2bf(tile[tx][r]);
}

// ---------------------------------------------------------------------------
// Pipelined GEMM K-loop. 128x128 tile, BK=64, double-buffered LDS (64 KB),
// depth-2 prefetch with counted vmcnt, XOR-swizzled LDS (slot ^= row&7).
// 4 waves (2x2), each wave 64x64 = 4x4 frags of 16x16x32 bf16 MFMA.
// ---------------------------------------------------------------------------

// stage one 128x64-elem (128 rows x 128 B) pair of tiles into LDS (linear dest,
// pre-swizzled global source per both-sides-or-neither rule)
__device__ __forceinline__ void stage_tile(const char* Ab, const char* Bb, long kbyte,
                                           long lda, long ldb, char* AsB, char* BsB,
                                           int tid) {
#pragma unroll
  for (int i = 0; i < 4; ++i) {
    const int o = i * 4096 + tid * 16;
    const int row = o >> 7;
    const int ls = ((((o >> 4) & 7) ^ (row & 7)) << 4);
    gload_lds16(Ab + (long)row * lda + kbyte + ls, AsB + o);
  }
#pragma unroll
  for (int i = 0; i < 4; ++i) {
    const int o = i * 4096 + tid * 16;
    const int row = o >> 7;
    const int ls = ((((o >> 4) & 7) ^ (row & 7)) << 4);
    gload_lds16(Bb + (long)row * ldb + kbyte + ls, BsB + o);
  }
}

// read one 16B fragment at (row, logical 16B-slot) from swizzled LDS tile
__device__ __forceinline__ bf16x8 frag_ld(const char* S, int row, int slot) {
  return *(const bf16x8*)(S + row * 128 + (((slot ^ (row & 7))) << 4));
}

__device__ __forceinline__ void gemm_kloop(const u16* __restrict__ A,
                                           const u16* __restrict__ Bt,
                                           int rowA0, int colB0, long K,
                                           char* AsB, char* BsB, f32x4 acc[4][4]) {
  const int tid = threadIdx.x;
  const int lane = tid & 63;
  const int wid = tid >> 6;
  const int wr = wid >> 1, wc = wid & 1;
  const long lda = K * 2;
  const long ldb = K * 2;
  const char* Ab = (const char*)A + (long)rowA0 * lda;
  const char* Bb = (const char*)Bt + (long)colB0 * ldb;
  const int arow = wr * 64 + (lane & 15);
  const int brow = wc * 64 + (lane & 15);
  const int hslot = lane >> 4;  // 0..3
  const int nt = (int)(K >> 6);

  stage_tile(Ab, Bb, 0, lda, ldb, AsB, BsB, tid);
  stage_tile(Ab, Bb, 128, lda, ldb, AsB + 32768, BsB + 32768, tid);

  for (int t = 0; t < nt; ++t) {
    const int cur = (t & 1) << 15;
    // wait for this tile's 8 staging loads (leave next tile's 8 in flight)
    if (t < nt - 1) asm volatile("s_waitcnt vmcnt(8)" ::: "memory");
    else            asm volatile("s_waitcnt vmcnt(0)" ::: "memory");
    __builtin_amdgcn_sched_barrier(0);
    __builtin_amdgcn_s_barrier();
    __builtin_amdgcn_sched_barrier(0);

    bf16x8 af[2][4], bfr[2][4];
#pragma unroll
    for (int s = 0; s < 2; ++s)
#pragma unroll
      for (int m = 0; m < 4; ++m) {
        af[s][m]  = frag_ld(AsB + cur, arow + m * 16, s * 4 + hslot);
        bfr[s][m] = frag_ld(BsB + cur, brow + m * 16, s * 4 + hslot);
      }
    asm volatile("s_waitcnt lgkmcnt(0)" ::: "memory");
    __builtin_amdgcn_sched_barrier(0);
    __builtin_amdgcn_s_barrier();  // all waves done reading buf[cur]
    __builtin_amdgcn_sched_barrier(0);

    if (t + 2 < nt)  // stage tile t+2 into the buffer just consumed
      stage_tile(Ab, Bb, (long)(t + 2) * 128, lda, ldb, AsB + cur, BsB + cur, tid);

    __builtin_amdgcn_s_setprio(1);
#pragma unroll
    for (int s = 0; s < 2; ++s)
#pragma unroll
      for (int m = 0; m < 4; ++m)
#pragma unroll
        for (int n = 0; n < 4; ++n)
          acc[m][n] = __builtin_amdgcn_mfma_f32_16x16x32_bf16(af[s][m], bfr[s][n],
                                                              acc[m][n], 0, 0, 0);
    __builtin_amdgcn_s_setprio(0);
    __builtin_amdgcn_sched_barrier(0);
  }
}

// ---------------------------------------------------------------------------
// Kernel C: GEMM1  phase = xb @ ct^T ; epilogue writes interleaved (cos,sin)
// as one u32 per element into CS[B, 2H]
// ---------------------------------------------------------------------------
__global__ __launch_bounds__(256) void gemm_phase(const u16* __restrict__ xb,
                                                  const u16* __restrict__ ct,
                                                  u32* __restrict__ cs) {
  __shared__ __align__(16) char smem[65536];
  const int rowA0 = blockIdx.y * 128;
  const int colB0 = blockIdx.x * 128;
  f32x4 acc[4][4];
#pragma unroll
  for (int m = 0; m < 4; ++m)
#pragma unroll
    for (int n = 0; n < 4; ++n)
#pragma unroll
      for (int j = 0; j < 4; ++j) acc[m][n][j] = 0.0f;

  gemm_kloop(xb, ct, rowA0, colB0, 2048, smem, smem + 16384, acc);

  const int lane = threadIdx.x & 63;
  const int wid = threadIdx.x >> 6;
  const int wr = wid >> 1, wc = wid & 1;
#pragma unroll
  for (int m = 0; m < 4; ++m) {
#pragma unroll
    for (int n = 0; n < 4; ++n) {
      const int col = colB0 + wc * 64 + n * 16 + (lane & 15);
#pragma unroll
      for (int j = 0; j < 4; ++j) {
        const int row = rowA0 + wr * 64 + m * 16 + (lane >> 4) * 4 + j;
        const float p = acc[m][n][j];
        const u32 w = (u32)f2bf(__cosf(p)) | ((u32)f2bf(__sinf(p)) << 16);
        cs[(long)row * H_DIM + col] = w;  // [B][2H] u16 = [B][H] u32
      }
    }
  }
}

// ---------------------------------------------------------------------------
// Kernel D: GEMM2  gain = CS[B,2H] @ AB[I,2H]^T + H*bias  (K=4096, fp32 out)
// ---------------------------------------------------------------------------
__global__ __launch_bounds__(256) void gemm_gain(const u16* __restrict__ cs,
                                                 const u16* __restrict__ ab,
                                                 const float* __restrict__ bias,
                                                 float* __restrict__ out) {
  __shared__ __align__(16) char smem[65536];
  const int rowA0 = blockIdx.y * 128;
  const int colB0 = blockIdx.x * 128;
  f32x4 acc[4][4];
#pragma unroll
  for (int m = 0; m < 4; ++m)
#pragma unroll
    for (int n = 0; n < 4; ++n)
#pragma unroll
      for (int j = 0; j < 4; ++j) acc[m][n][j] = 0.0f;

  gemm_kloop(cs, ab, rowA0, colB0, 4096, smem, smem + 16384, acc);

  const int lane = threadIdx.x & 63;
  const int wid = threadIdx.x >> 6;
  const int wr = wid >> 1, wc = wid & 1;
#pragma unroll
  for (int m = 0; m < 4; ++m) {
#pragma unroll
    for (int n = 0; n < 4; ++n) {
      const int col = colB0 + wc * 64 + n * 16 + (lane & 15);
      const float bv = 2048.0f * bias[col];
#pragma unroll
      for (int j = 0; j < 4; ++j) {
        const int row = rowA0 + wr * 64 + m * 16 + (lane >> 4) * 4 + j;
        out[(long)row * I_DIM + col] = acc[m][n][j] + bv;
      }
    }
  }
}

// ---------------------------------------------------------------------------
extern "C" void kernel_launch(void* const* d_in, const int* in_sizes, int n_in,
                              void* d_out, int out_size, void* d_ws, size_t ws_size,
                              hipStream_t stream) {
  const float* x     = (const float*)d_in[0];
  const float* coeff = (const float*)d_in[1];
  const float* an    = (const float*)d_in[2];
  const float* bn    = (const float*)d_in[3];
  const float* bias  = (const float*)d_in[4];
  float* out = (float*)d_out;

  char* ws = (char*)d_ws;
  u16* xb = (u16*)(ws);                  // 16 MB  [B,I] bf16
  u16* ct = (u16*)(ws + (16L << 20));    //  8 MB  [H,I] bf16 (coeff^T)
  u32* ab = (u32*)(ws + (24L << 20));    // 16 MB  [I,2H] bf16 interleaved (an,bn)
  u32* cs = (u32*)(ws + (40L << 20));    // 32 MB  [B,2H] bf16 interleaved (cos,sin)

  convert_ew<<<1024, 256, 0, stream>>>(x, an, bn, xb, ab);
  transpose_conv<<<dim3(H_DIM / 32, I_DIM / 32), dim3(32, 8), 0, stream>>>(coeff, ct);
  gemm_phase<<<dim3(H_DIM / 128, B_DIM / 128), 256, 0, stream>>>(xb, ct, cs);
  gemm_gain<<<dim3(I_DIM / 128, B_DIM / 128), 256, 0, stream>>>((const u16*)cs, (const u16*)ab,
                                                                bias, out);
}